// Round 9
// baseline (164.029 us; speedup 1.0000x reference)
//
#include <hip/hip_runtime.h>
#include <hip/hip_bf16.h>
#include <math.h>

#define D 256
#define KNB 32
#define NEG_SLOPE 0.2f
#define GRID_AGG 2000

// ws layout (floats):
//   [0..255]       w_src
//   [256..511]     w_tgt
//   [512..33279]   Wbf (65536 bf16)
//   [33280..53279] scores_t (N f32)
//   [53280..69663] prep partials (32x256 src + 32x256 tgt)
//   [69664.. ]     agg_bf (N*256 bf16)
#define PART_OFF 53280
#define AGG_OFF  69664

using bfrag = __attribute__((ext_vector_type(8))) short;   // 8 bf16 (4 VGPR)
using ffrag = __attribute__((ext_vector_type(4))) float;   // 4 f32 acc
using f32x4 = __attribute__((ext_vector_type(4))) float;   // native vec for nt loads

__device__ __forceinline__ unsigned short f2bf(float x) {
    __hip_bfloat16 h = __float2bfloat16(x);
    return *reinterpret_cast<unsigned short*>(&h);
}

// ---------------------------------------------------------------------------
// prep1: blocks 0..63 convert W -> bf16; blocks 64..95 compute 8-row partials
// of w_src/w_tgt with fully coalesced row reads.
// ---------------------------------------------------------------------------
__global__ __launch_bounds__(256) void prep1_kernel(
    const float* __restrict__ W, const float* __restrict__ a_src,
    const float* __restrict__ a_tgt, float* __restrict__ ws)
{
    int t = threadIdx.x;
    int b = blockIdx.x;
    if (b < 64) {
        float4 v = reinterpret_cast<const float4*>(W)[b * 256 + t];
        ushort4 u;
        u.x = f2bf(v.x); u.y = f2bf(v.y); u.z = f2bf(v.z); u.w = f2bf(v.w);
        reinterpret_cast<ushort4*>(ws + 512)[b * 256 + t] = u;
    } else {
        int bb = b - 64;               // 0..31, rows 8bb..8bb+7
        float ps = 0.f, pt = 0.f;
        #pragma unroll
        for (int oo = 0; oo < 8; ++oo) {
            int o = bb * 8 + oo;
            float wv = W[o * D + t];   // coalesced
            ps = fmaf(a_src[o], wv, ps);
            pt = fmaf(a_tgt[o], wv, pt);
        }
        ws[PART_OFF + bb * 256 + t]        = ps;
        ws[PART_OFF + 8192 + bb * 256 + t] = pt;
    }
}

// prep2: reduce the 32 partials -> w_src, w_tgt (1 block)
__global__ __launch_bounds__(256) void prep2_kernel(float* __restrict__ ws)
{
    int t = threadIdx.x;
    float s = 0.f, g = 0.f;
    #pragma unroll
    for (int j = 0; j < 32; ++j) {
        s += ws[PART_OFF + j * 256 + t];
        g += ws[PART_OFF + 8192 + j * 256 + t];
    }
    ws[t]     = s;   // w_src
    ws[D + t] = g;   // w_tgt
}

// ---------------------------------------------------------------------------
// scores_t[n] = nodes[n,:] . w_tgt   (one wave per node, 4 nodes/block)
// ---------------------------------------------------------------------------
__global__ __launch_bounds__(256) void scores_t_kernel(
    const float* __restrict__ nodes, const float* __restrict__ ws,
    float* __restrict__ scores_t, int N)
{
    int wid  = threadIdx.x >> 6;
    int lane = threadIdx.x & 63;
    int n = blockIdx.x * 4 + wid;
    if (n >= N) return;
    f32x4 v = __builtin_nontemporal_load(
        reinterpret_cast<const f32x4*>(nodes + (size_t)n * D) + lane);
    float4 w = reinterpret_cast<const float4*>(ws + D)[lane];
    float s = v.x * w.x + v.y * w.y + v.z * w.z + v.w * w.w;
    #pragma unroll
    for (int off = 1; off < 64; off <<= 1) s += __shfl_xor(s, off);
    if (lane == 0) scores_t[n] = s;
}

// ---------------------------------------------------------------------------
// Transposed 64-lane reduce of 8 per-lane row-partials.
// Out: lane l holds the FULL 64-lane sum for row 8w + (l&7).
// ---------------------------------------------------------------------------
__device__ __forceinline__ float xreduce8(const float* p, int lane)
{
    bool b0 = lane & 1, b1 = lane & 2, b2 = lane & 4;
    float s0_0 = (b0 ? p[1] : p[0]) + __shfl_xor(b0 ? p[0] : p[1], 1);
    float s0_1 = (b0 ? p[3] : p[2]) + __shfl_xor(b0 ? p[2] : p[3], 1);
    float s0_2 = (b0 ? p[5] : p[4]) + __shfl_xor(b0 ? p[4] : p[5], 1);
    float s0_3 = (b0 ? p[7] : p[6]) + __shfl_xor(b0 ? p[6] : p[7], 1);
    float s1_0 = (b1 ? s0_1 : s0_0) + __shfl_xor(b1 ? s0_0 : s0_1, 2);
    float s1_1 = (b1 ? s0_3 : s0_2) + __shfl_xor(b1 ? s0_2 : s0_3, 2);
    float s2   = (b2 ? s1_1 : s1_0) + __shfl_xor(b2 ? s1_0 : s1_1, 4);
    s2 += __shfl_xor(s2, 8);
    s2 += __shfl_xor(s2, 16);
    s2 += __shfl_xor(s2, 32);
    return s2;
}

// ---------------------------------------------------------------------------
// score + per-wave weighted partial for one node (all from registers).
// exp values stay in registers (xw via 8 intra-wave shfl); one part2 write.
// ---------------------------------------------------------------------------
__device__ __forceinline__ void score_agg(
    const f32x4* v, float st, const float4 wsv, int lane, int w,
    float4 (*part2)[64], float* wsum)
{
    float p[8];
    #pragma unroll
    for (int i = 0; i < 8; ++i)
        p[i] = fmaf(v[i].x, wsv.x, fmaf(v[i].y, wsv.y,
               fmaf(v[i].z, wsv.z, v[i].w * wsv.w)));
    float s2 = xreduce8(p, lane);
    float e = s2 + st; e = (e >= 0.f) ? e : NEG_SLOPE * e;
    float x = __expf(e);
    float d = x + __shfl_xor(x, 1);
    d += __shfl_xor(d, 2);
    d += __shfl_xor(d, 4);
    float xw[8];
    int base = lane & 56;
    #pragma unroll
    for (int i = 0; i < 8; ++i) xw[i] = __shfl(x, base | i);
    float4 acc = make_float4(0.f, 0.f, 0.f, 0.f);
    #pragma unroll
    for (int i = 0; i < 8; ++i) {
        acc.x = fmaf(xw[i], v[i].x, acc.x);
        acc.y = fmaf(xw[i], v[i].y, acc.y);
        acc.z = fmaf(xw[i], v[i].z, acc.z);
        acc.w = fmaf(xw[i], v[i].w, acc.w);
    }
    part2[w][lane] = acc;
    if (lane == 0) wsum[w] = d;
}

__device__ __forceinline__ void finalize_node(
    const float4 (*part2)[64], const float* wsum, int lane,
    unsigned short* dst)
{
    float4 q0 = part2[0][lane], q1 = part2[1][lane];
    float4 q2 = part2[2][lane], q3 = part2[3][lane];
    float inv = 1.f / (wsum[0] + wsum[1] + wsum[2] + wsum[3] + 1e-16f);
    float4 r;
    r.x = (q0.x + q1.x + q2.x + q3.x) * inv;
    r.y = (q0.y + q1.y + q2.y + q3.y) * inv;
    r.z = (q0.z + q1.z + q2.z + q3.z) * inv;
    r.w = (q0.w + q1.w + q2.w + q3.w) * inv;
    ushort4 u;
    u.x = f2bf(r.x); u.y = f2bf(r.y); u.z = f2bf(r.z); u.w = f2bf(r.w);
    reinterpret_cast<ushort4*>(dst)[lane] = u;
}

// ---------------------------------------------------------------------------
// Persistent pipelined attention+aggregate. GRID_AGG grid-stride blocks;
// while node i is computed from registers, node i+1's 8 nt loads are in
// flight (compiler emits counted vmcnt). 1 barrier/node, double-buffered
// part2. Tiles never touch LDS; nt loads bypass L2/L3 allocate.
// ---------------------------------------------------------------------------
__global__ __launch_bounds__(256) void attn_agg_kernel(
    const float* __restrict__ neighbors, const float* __restrict__ ws,
    const float* __restrict__ scores_t, unsigned short* __restrict__ aggbf, int N)
{
    __shared__ __align__(16) float4 part2[2][4][64];   // 8 KB
    __shared__ float wsum[2][4];

    const int t    = threadIdx.x;
    const int lane = t & 63;
    const int w    = t >> 6;
    const int n0   = blockIdx.x;
    const int GRID = GRID_AGG;

    const float4 wsv = reinterpret_cast<const float4*>(ws)[lane];

    const int nd = (n0 < N) ? ((N - 1 - n0) / GRID + 1) : 0;
    if (nd == 0) return;

    f32x4 vA[8], vB[8];
    float stA = 0.f, stB = 0.f;

    // prologue: node 0 of this block
    {
        const f32x4* tp = reinterpret_cast<const f32x4*>(
            neighbors + (size_t)n0 * (KNB * D));
        #pragma unroll
        for (int i = 0; i < 8; ++i)
            vA[i] = __builtin_nontemporal_load(tp + (8 * w + i) * 64 + lane);
        stA = scores_t[n0];
    }

    const int npairs = (nd + 1) >> 1;
    for (int it = 0; it < npairs; ++it) {
        const int idxA = 2 * it;
        const int nA = n0 + idxA * GRID;
        const int nB = nA + GRID;
        const bool hasB  = (idxA + 1) < nd;
        const bool hasA2 = (idxA + 2) < nd;

        if (hasB) {   // prefetch B under A's compute
            const f32x4* tp = reinterpret_cast<const f32x4*>(
                neighbors + (size_t)nB * (KNB * D));
            #pragma unroll
            for (int i = 0; i < 8; ++i)
                vB[i] = __builtin_nontemporal_load(tp + (8 * w + i) * 64 + lane);
            stB = scores_t[nB];
        }

        score_agg(vA, stA, wsv, lane, w, part2[0], wsum[0]);
        __syncthreads();
        if (w == 0) finalize_node(part2[0], wsum[0], lane, aggbf + (size_t)nA * D);

        if (hasA2) {  // prefetch next A under B's compute
            const int nA2 = nA + 2 * GRID;
            const f32x4* tp = reinterpret_cast<const f32x4*>(
                neighbors + (size_t)nA2 * (KNB * D));
            #pragma unroll
            for (int i = 0; i < 8; ++i)
                vA[i] = __builtin_nontemporal_load(tp + (8 * w + i) * 64 + lane);
            stA = scores_t[nA2];
        }

        if (hasB) {
            score_agg(vB, stB, wsv, lane, w, part2[1], wsum[1]);
            __syncthreads();
            if (w == 1) finalize_node(part2[1], wsum[1], lane, aggbf + (size_t)nB * D);
        }
    }
}

// ---------------------------------------------------------------------------
// out = elu(agg_bf @ Wbf^T + bias), f32 out. One wave per block, 16 rows.
// mfma_f32_16x16x32_bf16: D lane l: row=(l>>4)*4+reg, col=l&15
// ---------------------------------------------------------------------------
__global__ __launch_bounds__(64) void out_gemm_kernel(
    const unsigned short* __restrict__ aggbf,
    const unsigned short* __restrict__ wbf,
    const float* __restrict__ bias, float* __restrict__ out, int N)
{
    int l = threadIdx.x;
    int m0 = blockIdx.x * 16;
    if (m0 >= N) return;
    int lr = l & 15, lk = l >> 4;

    ffrag acc[16];
    #pragma unroll
    for (int nf = 0; nf < 16; ++nf) acc[nf] = ffrag{0.f, 0.f, 0.f, 0.f};

    #pragma unroll
    for (int ks = 0; ks < 8; ++ks) {
        bfrag a = *reinterpret_cast<const bfrag*>(
            aggbf + (size_t)(m0 + lr) * D + ks * 32 + lk * 8);
        #pragma unroll
        for (int nf = 0; nf < 16; ++nf) {
            bfrag b = *reinterpret_cast<const bfrag*>(
                wbf + (size_t)(nf * 16 + lr) * D + ks * 32 + lk * 8);
            acc[nf] = __builtin_amdgcn_mfma_f32_16x16x32_bf16(a, b, acc[nf], 0, 0, 0);
        }
    }

    #pragma unroll
    for (int nf = 0; nf < 16; ++nf) {
        int col = nf * 16 + lr;
        float bv = bias[col];
        #pragma unroll
        for (int r = 0; r < 4; ++r) {
            int m = m0 + lk * 4 + r;
            float x = acc[nf][r] + bv;
            x = (x > 0.f) ? x : expm1f(x);
            out[(size_t)m * D + col] = x;
        }
    }
}

// ---------------------------------------------------------------------------
extern "C" void kernel_launch(void* const* d_in, const int* in_sizes, int n_in,
                              void* d_out, int out_size, void* d_ws, size_t ws_size,
                              hipStream_t stream) {
    const float* nodes     = (const float*)d_in[0];
    const float* neighbors = (const float*)d_in[1];
    const float* W         = (const float*)d_in[2];
    const float* a_src     = (const float*)d_in[3];
    const float* a_tgt     = (const float*)d_in[4];
    const float* bias      = (const float*)d_in[5];
    float* out = (float*)d_out;
    float* ws  = (float*)d_ws;

    int N = in_sizes[0] / D;                                  // 20000
    unsigned short* wbf   = (unsigned short*)(ws + 512);
    float* scores_t       = ws + 33280;
    unsigned short* aggbf = (unsigned short*)(ws + AGG_OFF);

    hipLaunchKernelGGL(prep1_kernel, dim3(96), dim3(256), 0, stream,
                       W, a_src, a_tgt, ws);
    hipLaunchKernelGGL(prep2_kernel, dim3(1), dim3(256), 0, stream, ws);
    hipLaunchKernelGGL(scores_t_kernel, dim3((N + 3) / 4), dim3(256), 0, stream,
                       nodes, ws, scores_t, N);
    hipLaunchKernelGGL(attn_agg_kernel, dim3(GRID_AGG), dim3(256), 0, stream,
                       neighbors, ws, scores_t, aggbf, N);
    hipLaunchKernelGGL(out_gemm_kernel, dim3((N + 15) / 16), dim3(64), 0, stream,
                       aggbf, wbf, bias, out, N);
}

// Round 10
// 157.441 us; speedup vs baseline: 1.0418x; 1.0418x over previous
//
#include <hip/hip_runtime.h>
#include <hip/hip_bf16.h>
#include <math.h>

#define D 256
#define KNB 32
#define NEG_SLOPE 0.2f

// ws layout (floats):
//   [0..255]       w_src
//   [256..511]     w_tgt
//   [512..33279]   Wbf (65536 bf16)
//   [33280..53279] (unused)
//   [53280..69663] prep partials (32x256 src + 32x256 tgt)
//   [69664.. ]     agg_bf (N*256 bf16)
#define PART_OFF 53280
#define AGG_OFF  69664

using bfrag = __attribute__((ext_vector_type(8))) short;   // 8 bf16 (4 VGPR)
using ffrag = __attribute__((ext_vector_type(4))) float;   // 4 f32 acc
using f32x4 = __attribute__((ext_vector_type(4))) float;   // native vec for nt loads

__device__ __forceinline__ unsigned short f2bf(float x) {
    __hip_bfloat16 h = __float2bfloat16(x);
    return *reinterpret_cast<unsigned short*>(&h);
}

// ---------------------------------------------------------------------------
// prep1: blocks 0..63 convert W -> bf16; blocks 64..95 compute 8-row partials
// of w_src/w_tgt with fully coalesced row reads.
// ---------------------------------------------------------------------------
__global__ __launch_bounds__(256) void prep1_kernel(
    const float* __restrict__ W, const float* __restrict__ a_src,
    const float* __restrict__ a_tgt, float* __restrict__ ws)
{
    int t = threadIdx.x;
    int b = blockIdx.x;
    if (b < 64) {
        float4 v = reinterpret_cast<const float4*>(W)[b * 256 + t];
        ushort4 u;
        u.x = f2bf(v.x); u.y = f2bf(v.y); u.z = f2bf(v.z); u.w = f2bf(v.w);
        reinterpret_cast<ushort4*>(ws + 512)[b * 256 + t] = u;
    } else {
        int bb = b - 64;               // 0..31, rows 8bb..8bb+7
        float ps = 0.f, pt = 0.f;
        #pragma unroll
        for (int oo = 0; oo < 8; ++oo) {
            int o = bb * 8 + oo;
            float wv = W[o * D + t];   // coalesced
            ps = fmaf(a_src[o], wv, ps);
            pt = fmaf(a_tgt[o], wv, pt);
        }
        ws[PART_OFF + bb * 256 + t]        = ps;
        ws[PART_OFF + 8192 + bb * 256 + t] = pt;
    }
}

// prep2: reduce the 32 partials -> w_src, w_tgt (1 block)
__global__ __launch_bounds__(256) void prep2_kernel(float* __restrict__ ws)
{
    int t = threadIdx.x;
    float s = 0.f, g = 0.f;
    #pragma unroll
    for (int j = 0; j < 32; ++j) {
        s += ws[PART_OFF + j * 256 + t];
        g += ws[PART_OFF + 8192 + j * 256 + t];
    }
    ws[t]     = s;   // w_src
    ws[D + t] = g;   // w_tgt
}

// ---------------------------------------------------------------------------
// Transposed 64-lane reduce of 8 per-lane row-partials.
// Out: lane l holds the FULL 64-lane sum for row 8w + (l&7).
// ---------------------------------------------------------------------------
__device__ __forceinline__ float xreduce8(const float* p, int lane)
{
    bool b0 = lane & 1, b1 = lane & 2, b2 = lane & 4;
    float s0_0 = (b0 ? p[1] : p[0]) + __shfl_xor(b0 ? p[0] : p[1], 1);
    float s0_1 = (b0 ? p[3] : p[2]) + __shfl_xor(b0 ? p[2] : p[3], 1);
    float s0_2 = (b0 ? p[5] : p[4]) + __shfl_xor(b0 ? p[4] : p[5], 1);
    float s0_3 = (b0 ? p[7] : p[6]) + __shfl_xor(b0 ? p[6] : p[7], 1);
    float s1_0 = (b1 ? s0_1 : s0_0) + __shfl_xor(b1 ? s0_0 : s0_1, 2);
    float s1_1 = (b1 ? s0_3 : s0_2) + __shfl_xor(b1 ? s0_2 : s0_3, 2);
    float s2   = (b2 ? s1_1 : s1_0) + __shfl_xor(b2 ? s1_0 : s1_1, 4);
    s2 += __shfl_xor(s2, 8);
    s2 += __shfl_xor(s2, 16);
    s2 += __shfl_xor(s2, 32);
    return s2;
}

// ---------------------------------------------------------------------------
// Fused scores_t + attention + aggregate (R8 2-node structure).
// Cached nodes loads issued FIRST, then 16 nt neighbor loads; the score_t
// dot (64-lane reduce) runs under the neighbor-load shadow via counted
// vmcnt. Neighbors never touch LDS; nt bypasses L2/L3 allocate.
// ---------------------------------------------------------------------------
__global__ __launch_bounds__(256) void attn_agg_kernel(
    const float* __restrict__ nodes, const float* __restrict__ neighbors,
    const float* __restrict__ ws, unsigned short* __restrict__ aggbf, int N)
{
    __shared__ float spA[KNB], spB[KNB];
    __shared__ float wsumA[4], wsumB[4];
    __shared__ __align__(16) float4 part2A[4][64];
    __shared__ __align__(16) float4 part2B[4][64];

    const int t    = threadIdx.x;
    const int lane = t & 63;
    const int w    = t >> 6;
    const int nA   = blockIdx.x * 2;
    const bool hasB = (nA + 1 < N);
    const int nB   = hasB ? nA + 1 : nA;

    // cached small loads FIRST (w_src, w_tgt, node rows)
    const float4 wsv = reinterpret_cast<const float4*>(ws)[lane];
    const float4 wtv = reinterpret_cast<const float4*>(ws + D)[lane];
    const float4 nvA = reinterpret_cast<const float4*>(nodes + (size_t)nA * D)[lane];
    const float4 nvB = reinterpret_cast<const float4*>(nodes + (size_t)nB * D)[lane];

    // nt neighbor tile loads (newest outstanding -> counted vmcnt for above)
    const f32x4* tA = reinterpret_cast<const f32x4*>(neighbors + (size_t)nA * (KNB * D));
    const f32x4* tB = reinterpret_cast<const f32x4*>(neighbors + (size_t)nB * (KNB * D));
    f32x4 vA[8], vB[8];
    #pragma unroll
    for (int i = 0; i < 8; ++i)
        vA[i] = __builtin_nontemporal_load(tA + (8 * w + i) * 64 + lane);
    #pragma unroll
    for (int i = 0; i < 8; ++i)
        vB[i] = __builtin_nontemporal_load(tB + (8 * w + i) * 64 + lane);

    // score_t dots under the neighbor-load shadow
    float stA, stB;
    {
        float sa = nvA.x * wtv.x + nvA.y * wtv.y + nvA.z * wtv.z + nvA.w * wtv.w;
        float sb = nvB.x * wtv.x + nvB.y * wtv.y + nvB.z * wtv.z + nvB.w * wtv.w;
        #pragma unroll
        for (int off = 1; off < 64; off <<= 1) {
            sa += __shfl_xor(sa, off);
            sb += __shfl_xor(sb, off);
        }
        stA = sa; stB = sb;
    }

    // ---- node A scores ----
    {
        float p[8];
        #pragma unroll
        for (int i = 0; i < 8; ++i)
            p[i] = fmaf(vA[i].x, wsv.x, fmaf(vA[i].y, wsv.y,
                   fmaf(vA[i].z, wsv.z, vA[i].w * wsv.w)));
        float s2 = xreduce8(p, lane);
        float e = s2 + stA; e = (e >= 0.f) ? e : NEG_SLOPE * e;
        float x = __expf(e);
        float d = x + __shfl_xor(x, 1);
        d += __shfl_xor(d, 2);
        d += __shfl_xor(d, 4);
        if (lane < 8) spA[8 * w + lane] = x;
        if (lane == 0) wsumA[w] = d;
    }
    // ---- node B scores ----
    {
        float p[8];
        #pragma unroll
        for (int i = 0; i < 8; ++i)
            p[i] = fmaf(vB[i].x, wsv.x, fmaf(vB[i].y, wsv.y,
                   fmaf(vB[i].z, wsv.z, vB[i].w * wsv.w)));
        float s2 = xreduce8(p, lane);
        float e = s2 + stB; e = (e >= 0.f) ? e : NEG_SLOPE * e;
        float x = __expf(e);
        float d = x + __shfl_xor(x, 1);
        d += __shfl_xor(d, 2);
        d += __shfl_xor(d, 4);
        if (lane < 8) spB[8 * w + lane] = x;
        if (lane == 0) wsumB[w] = d;
    }
    __syncthreads();

    // ---- per-wave weighted column partials (pure register) ----
    {
        float xw[8];
        #pragma unroll
        for (int i = 0; i < 8; ++i) xw[i] = spA[8 * w + i];   // uniform bcast
        float4 acc = make_float4(0.f, 0.f, 0.f, 0.f);
        #pragma unroll
        for (int i = 0; i < 8; ++i) {
            acc.x = fmaf(xw[i], vA[i].x, acc.x);
            acc.y = fmaf(xw[i], vA[i].y, acc.y);
            acc.z = fmaf(xw[i], vA[i].z, acc.z);
            acc.w = fmaf(xw[i], vA[i].w, acc.w);
        }
        part2A[w][lane] = acc;
    }
    {
        float xw[8];
        #pragma unroll
        for (int i = 0; i < 8; ++i) xw[i] = spB[8 * w + i];
        float4 acc = make_float4(0.f, 0.f, 0.f, 0.f);
        #pragma unroll
        for (int i = 0; i < 8; ++i) {
            acc.x = fmaf(xw[i], vB[i].x, acc.x);
            acc.y = fmaf(xw[i], vB[i].y, acc.y);
            acc.z = fmaf(xw[i], vB[i].z, acc.z);
            acc.w = fmaf(xw[i], vB[i].w, acc.w);
        }
        part2B[w][lane] = acc;
    }
    __syncthreads();

    // ---- finalize: wave0 -> node A, wave1 -> node B ----
    if (w == 0) {
        float4 q0 = part2A[0][lane], q1 = part2A[1][lane];
        float4 q2 = part2A[2][lane], q3 = part2A[3][lane];
        float inv = 1.f / (wsumA[0] + wsumA[1] + wsumA[2] + wsumA[3] + 1e-16f);
        float4 r;
        r.x = (q0.x + q1.x + q2.x + q3.x) * inv;
        r.y = (q0.y + q1.y + q2.y + q3.y) * inv;
        r.z = (q0.z + q1.z + q2.z + q3.z) * inv;
        r.w = (q0.w + q1.w + q2.w + q3.w) * inv;
        ushort4 u;
        u.x = f2bf(r.x); u.y = f2bf(r.y); u.z = f2bf(r.z); u.w = f2bf(r.w);
        reinterpret_cast<ushort4*>(aggbf + (size_t)nA * D)[lane] = u;
    } else if (w == 1 && hasB) {
        float4 q0 = part2B[0][lane], q1 = part2B[1][lane];
        float4 q2 = part2B[2][lane], q3 = part2B[3][lane];
        float inv = 1.f / (wsumB[0] + wsumB[1] + wsumB[2] + wsumB[3] + 1e-16f);
        float4 r;
        r.x = (q0.x + q1.x + q2.x + q3.x) * inv;
        r.y = (q0.y + q1.y + q2.y + q3.y) * inv;
        r.z = (q0.z + q1.z + q2.z + q3.z) * inv;
        r.w = (q0.w + q1.w + q2.w + q3.w) * inv;
        ushort4 u;
        u.x = f2bf(r.x); u.y = f2bf(r.y); u.z = f2bf(r.z); u.w = f2bf(r.w);
        reinterpret_cast<ushort4*>(aggbf + (size_t)nB * D)[lane] = u;
    }
}

// ---------------------------------------------------------------------------
// out = elu(agg_bf @ Wbf^T + bias), f32 out. One wave per block, 16 rows.
// mfma_f32_16x16x32_bf16: D lane l: row=(l>>4)*4+reg, col=l&15
// ---------------------------------------------------------------------------
__global__ __launch_bounds__(64) void out_gemm_kernel(
    const unsigned short* __restrict__ aggbf,
    const unsigned short* __restrict__ wbf,
    const float* __restrict__ bias, float* __restrict__ out, int N)
{
    int l = threadIdx.x;
    int m0 = blockIdx.x * 16;
    if (m0 >= N) return;
    int lr = l & 15, lk = l >> 4;

    ffrag acc[16];
    #pragma unroll
    for (int nf = 0; nf < 16; ++nf) acc[nf] = ffrag{0.f, 0.f, 0.f, 0.f};

    #pragma unroll
    for (int ks = 0; ks < 8; ++ks) {
        bfrag a = *reinterpret_cast<const bfrag*>(
            aggbf + (size_t)(m0 + lr) * D + ks * 32 + lk * 8);
        #pragma unroll
        for (int nf = 0; nf < 16; ++nf) {
            bfrag b = *reinterpret_cast<const bfrag*>(
                wbf + (size_t)(nf * 16 + lr) * D + ks * 32 + lk * 8);
            acc[nf] = __builtin_amdgcn_mfma_f32_16x16x32_bf16(a, b, acc[nf], 0, 0, 0);
        }
    }

    #pragma unroll
    for (int nf = 0; nf < 16; ++nf) {
        int col = nf * 16 + lr;
        float bv = bias[col];
        #pragma unroll
        for (int r = 0; r < 4; ++r) {
            int m = m0 + lk * 4 + r;
            float x = acc[nf][r] + bv;
            x = (x > 0.f) ? x : expm1f(x);
            out[(size_t)m * D + col] = x;
        }
    }
}

// ---------------------------------------------------------------------------
extern "C" void kernel_launch(void* const* d_in, const int* in_sizes, int n_in,
                              void* d_out, int out_size, void* d_ws, size_t ws_size,
                              hipStream_t stream) {
    const float* nodes     = (const float*)d_in[0];
    const float* neighbors = (const float*)d_in[1];
    const float* W         = (const float*)d_in[2];
    const float* a_src     = (const float*)d_in[3];
    const float* a_tgt     = (const float*)d_in[4];
    const float* bias      = (const float*)d_in[5];
    float* out = (float*)d_out;
    float* ws  = (float*)d_ws;

    int N = in_sizes[0] / D;                                  // 20000
    unsigned short* wbf   = (unsigned short*)(ws + 512);
    unsigned short* aggbf = (unsigned short*)(ws + AGG_OFF);

    hipLaunchKernelGGL(prep1_kernel, dim3(96), dim3(256), 0, stream,
                       W, a_src, a_tgt, ws);
    hipLaunchKernelGGL(prep2_kernel, dim3(1), dim3(256), 0, stream, ws);
    hipLaunchKernelGGL(attn_agg_kernel, dim3((N + 1) / 2), dim3(256), 0, stream,
                       nodes, neighbors, ws, aggbf, N);
    hipLaunchKernelGGL(out_gemm_kernel, dim3((N + 15) / 16), dim3(64), 0, stream,
                       aggbf, wbf, bias, out, N);
}